// Round 15
// baseline (344.149 us; speedup 1.0000x reference)
//
#include <hip/hip_runtime.h>
#include <hip/hip_bf16.h>

typedef float f32x4 __attribute__((ext_vector_type(4)));
typedef short bf16x8 __attribute__((ext_vector_type(8)));
typedef unsigned short us8 __attribute__((ext_vector_type(8)));

__device__ __forceinline__ unsigned short f2bf(float f) {
  union { float f; unsigned u; } v; v.f = f;
  return (unsigned short)((v.u + 0x8000u) >> 16);   // round-half-up bf16
}
__device__ __forceinline__ float bf2f(unsigned short u) {
  union { unsigned u; float f; } v; v.u = ((unsigned)u) << 16;
  return v.f;
}

// ---------------------------------------------------------------------------
// Kernel 1: VmatT[b][n][p] (bf16), n = c*16+u*4+v (256), p = pi*64+pj (4096)
// ---------------------------------------------------------------------------
__global__ __launch_bounds__(256) void prep_vmat(const float* __restrict__ x,
                                                 unsigned short* __restrict__ vmatT) {
  int t = blockIdx.x * 256 + threadIdx.x;
  int pc = t & 511;
  int n  = (t >> 9) & 255;
  int b  = t >> 17;
  int c = n >> 4, u = (n >> 2) & 3, v = n & 3;
  int pi = pc >> 3;
  int pj0 = (pc & 7) << 3;
  int row = 2 * pi + u - 1;
  row = row < 0 ? 0 : (row > 127 ? 127 : row);
  const float* xr = x + ((size_t)(b * 16 + c) * 128 + row) * 128;
  us8 o;
#pragma unroll
  for (int e = 0; e < 8; ++e) {
    int col = 2 * (pj0 + e) + v - 1;
    col = col < 0 ? 0 : (col > 127 ? 127 : col);
    o[e] = f2bf(xr[col]);
  }
  *reinterpret_cast<us8*>(vmatT + (size_t)t * 8) = o;
}

// ---------------------------------------------------------------------------
// Kernel 2: partial[ks][b][q][n] (bf16) = sum_{p in half ks} scores*VmatT
// B-REUSE GEMM. BQ=256 (512 thr, 8 waves x 32 q-rows: 2 M-frags/wave),
// K-split 2 (block K=2048, 32 K-tiles of 64). grid 256 = 1 block/CU.
// Each bv ds_read feeds 2 MFMAs -> per-CU LDS pipe 3072 cyc vs 6240-cyc
// HBM budget per iter (49%, was ~100% co-saturated in R7/R13). biters/CU
// halves to 32. In-flight at wait kept at R13's proven 96 KB/CU.
//  - A: per-lane direct frags (rows wq*32+{0,16}+l15, k=l16*8), 8 dwordx4
//    per tile, reg-staged 2 tiles ahead (rE/rO); CONV extracts BEFORE reload.
//  - B: ring-4 x 32 KB (128 KB LDS), global_load_lds 16B x4/thread, staged
//    3 TILES AHEAD. WAR: buf (kt+3)&3 last read at iter kt-1. RAW: B(kt)
//    drained at wait of kt-2.
//  - iter kt: CONV; STAGE_B(kt+3); LOAD_A(kt+2); 64 MFMA (32 ds_read);
//    vmcnt(12) drains exactly {B(kt+2), A(kt+1)}, leaves {B(kt+3), A(kt+2)}
//    = 96 KB/CU riding the barrier.
//  - VGPR ~230 (acc 128 + A-stage 64 + frags/addr) under (512,2) = 256 cap.
//  - uniform 32 iters; tail wrap loads (&31) kept alive by asm.
// ---------------------------------------------------------------------------
__global__ __launch_bounds__(512, 2) void gemm_scores_vmat(
    const float* __restrict__ scores,
    const unsigned short* __restrict__ vmatT,
    unsigned short* __restrict__ AmatP) {
  __shared__ unsigned short ldsB[4][16384];   // 4 x (256 rows x 64 bf16)

  int bid = blockIdx.x;                        // 256 blocks = 1/CU
  int batch = bid & 7;                         // = XCD id
  int inner = bid >> 3;                        // 0..31
  int qb = (inner & 15) << 8;                  // 16 q-blocks of 256
  int ksp = inner >> 4;                        // K-split half
  const int phase = inner & 31;

  const int t = threadIdx.x;
  const int lane = t & 63;
  const int wq = t >> 6;                       // wave id 0..7 = 32-row M slice
  const int l15 = lane & 15, l16 = lane >> 4;

  const size_t kbase = (size_t)ksp * 2048;
  // A: per-lane fragment base (rows = qb + wq*32 + {0,16} + l15, k = l16*8)
  const float* aLane = scores +
      ((size_t)(batch * 4096 + qb + wq * 32 + l15)) * 4096 + kbase + l16 * 8;
  const unsigned short* Vb = vmatT + (size_t)batch * 256 * 4096 + kbase;

  // B staging: 2048 chunks of 16B; thread t takes c = t + i*512, i=0..3.
  const unsigned short* bSrc[4];
#pragma unroll
  for (int i = 0; i < 4; ++i) {
    int c = t + i * 512;
    int gs = (c & 7) ^ ((c >> 3) & 7);         // pre-swizzled source slot
    bSrc[i] = Vb + (size_t)(c >> 3) * 4096 + gs * 8;
  }
  const int pos0 = (l16 ^ (l15 & 7)) << 3;     // swizzled slot, ks=0 (elems)

  f32x4 acc[2][16];
#pragma unroll
  for (int m = 0; m < 2; ++m)
#pragma unroll
    for (int ni = 0; ni < 16; ++ni) acc[m][ni] = (f32x4){0.f, 0.f, 0.f, 0.f};

  f32x4 rE[8], rO[8];       // two named A sets (2 frag-rows x 4 dwordx4)
  bf16x8 fa[2][2];          // [m][ks], static indices only

#define SB __builtin_amdgcn_sched_barrier(0)
#define STAGE_B(kt, bufi)                                                     \
  {                                                                           \
    int kp_ = ((kt) + phase) & 31;                                            \
    _Pragma("unroll") for (int i = 0; i < 4; ++i)                             \
        __builtin_amdgcn_global_load_lds(                                     \
            (const __attribute__((address_space(1))) void*)(bSrc[i] + (size_t)kp_ * 64), \
            (__attribute__((address_space(3))) void*)&ldsB[bufi][(t + i * 512) * 8], \
            16, 0, 0);                                                        \
  }
#define LOAD_A(kt, rr)                                                        \
  {                                                                           \
    int kp_ = ((kt) + phase) & 31;                                            \
    const float* ap_ = aLane + (size_t)kp_ * 64;                              \
    rr[0] = *(const f32x4*)(ap_);                                             \
    rr[1] = *(const f32x4*)(ap_ + 4);                                         \
    rr[2] = *(const f32x4*)(ap_ + 32);                                        \
    rr[3] = *(const f32x4*)(ap_ + 36);                                        \
    const float* aq_ = ap_ + (size_t)16 * 4096;                               \
    rr[4] = *(const f32x4*)(aq_);                                             \
    rr[5] = *(const f32x4*)(aq_ + 4);                                         \
    rr[6] = *(const f32x4*)(aq_ + 32);                                        \
    rr[7] = *(const f32x4*)(aq_ + 36);                                        \
  }
#define CONV(rr)                                                              \
  {                                                                           \
    _Pragma("unroll") for (int e = 0; e < 4; ++e) {                           \
      fa[0][0][e]     = (short)f2bf(rr[0][e]);                                \
      fa[0][0][e + 4] = (short)f2bf(rr[1][e]);                                \
      fa[0][1][e]     = (short)f2bf(rr[2][e]);                                \
      fa[0][1][e + 4] = (short)f2bf(rr[3][e]);                                \
      fa[1][0][e]     = (short)f2bf(rr[4][e]);                                \
      fa[1][0][e + 4] = (short)f2bf(rr[5][e]);                                \
      fa[1][1][e]     = (short)f2bf(rr[6][e]);                                \
      fa[1][1][e + 4] = (short)f2bf(rr[7][e]);                                \
    }                                                                         \
  }
#define MFMAS(bufi)                                                           \
  {                                                                           \
    _Pragma("unroll") for (int ks = 0; ks < 2; ++ks)                          \
        _Pragma("unroll") for (int ni = 0; ni < 16; ++ni) {                   \
      bf16x8 bv = *(const bf16x8*)(&ldsB[bufi][0] +                           \
                                   (ni * 16 + l15) * 64 + (pos0 ^ (ks * 32))); \
      acc[0][ni] = __builtin_amdgcn_mfma_f32_16x16x32_bf16(fa[0][ks], bv,     \
                                                           acc[0][ni], 0, 0, 0); \
      acc[1][ni] = __builtin_amdgcn_mfma_f32_16x16x32_bf16(fa[1][ks], bv,     \
                                                           acc[1][ni], 0, 0, 0); \
    }                                                                         \
  }
// iter kt (buf m = kt&3): consume A(kt) from rr + B(kt) from buf m
#define BODY(m, kt, rr)                                                       \
  {                                                                           \
    CONV(rr);                   /* extract BEFORE reload */                   \
    SB;                                                                       \
    STAGE_B((kt) + 3, ((m) + 3) & 3);                                         \
    SB;                                                                       \
    LOAD_A((kt) + 2, rr);                                                     \
    SB;                                                                       \
    MFMAS(m);                                                                 \
    SB;                                                                       \
    asm volatile("s_waitcnt vmcnt(12)" ::: "memory");                         \
    SB;                                                                       \
    __builtin_amdgcn_s_barrier();                                             \
    SB;                                                                       \
  }

  // ---- prologue: issue B0,B1,A0,B2,A1 (28 instr); vmcnt(12) drains exactly
  // {B0,B1,A0}; post-wait FIFO = {B2, A1} = 12 = steady-state entry.
  STAGE_B(0, 0);
  SB;
  STAGE_B(1, 1);
  SB;
  LOAD_A(0, rE);
  SB;
  STAGE_B(2, 2);
  SB;
  LOAD_A(1, rO);
  SB;
  asm volatile("s_waitcnt vmcnt(12)" ::: "memory");  // B0,B1,A0 landed
  SB;
  __builtin_amdgcn_s_barrier();
  SB;

  // ---- main loop: 32 uniform iters, period-4 bufs, period-2 A sets
  for (int kt = 0; kt < 32; kt += 4) {
    BODY(0, kt, rE);
    BODY(1, kt + 1, rO);
    BODY(2, kt + 2, rE);
    BODY(3, kt + 3, rO);
  }

  // keep tail wrap prefetches live so the vmcnt FIFO accounting stays exact
  asm volatile("" ::"v"(rE[0][0]), "v"(rE[3][0]), "v"(rE[5][0]), "v"(rE[7][0]),
               "v"(rO[0][0]), "v"(rO[3][0]), "v"(rO[5][0]), "v"(rO[7][0]));

#undef SB
#undef STAGE_B
#undef LOAD_A
#undef CONV
#undef MFMAS
#undef BODY

  // C-write to partial ksp: rows qb+wq*32+m*16+l16*4+j, col ni*16+l15
  unsigned short* Ao = AmatP + (size_t)ksp * 8 * 4096 * 256 +
                       ((size_t)(batch * 4096 + qb + wq * 32)) * 256;
#pragma unroll
  for (int m = 0; m < 2; ++m)
#pragma unroll
    for (int ni = 0; ni < 16; ++ni)
#pragma unroll
      for (int j = 0; j < 4; ++j)
        Ao[(size_t)(m * 16 + l16 * 4 + j) * 256 + ni * 16 + l15] =
            f2bf(acc[m][ni][j]);
}

// ---------------------------------------------------------------------------
// Kernel 3: out = x + alpha/4 * gathered conv_transpose contributions,
// summing the two K-split partials.
// ---------------------------------------------------------------------------
__global__ __launch_bounds__(256) void epilogue_kernel(
    const float* __restrict__ x, const unsigned short* __restrict__ AmatP,
    const float* __restrict__ alpha, float* __restrict__ out) {
  int b = blockIdx.x >> 7;
  int h = blockIdx.x & 127;
  int t = threadIdx.x;
  int w = t & 127;
  int cg = t >> 7;

  int ihi = (h + 1) >> 1, u_hi = (h + 1) & 1;
  int jhi = (w + 1) >> 1, v_hi = (w + 1) & 1;
  bool vi_hi = (ihi <= 63), vi_lo = (ihi >= 1);
  bool vj_hi = (jhi <= 63), vj_lo = (jhi >= 1);

  float al = alpha[0] * 0.25f;
  const unsigned short* A0 = AmatP + (size_t)b * 4096 * 256;
  const unsigned short* A1 = A0 + (size_t)8 * 4096 * 256;

#pragma unroll
  for (int cc = 0; cc < 8; ++cc) {
    int c = cg * 8 + cc;
    float s = 0.f;
    if (vi_hi) {
      size_t base = (size_t)(ihi * 64) * 256 + c * 16 + u_hi * 4;
      if (vj_hi) {
        size_t i0 = base + jhi * 256 + v_hi;
        s += bf2f(A0[i0]) + bf2f(A1[i0]);
      }
      if (vj_lo) {
        size_t i0 = base + (jhi - 1) * 256 + v_hi + 2;
        s += bf2f(A0[i0]) + bf2f(A1[i0]);
      }
    }
    if (vi_lo) {
      size_t base = (size_t)((ihi - 1) * 64) * 256 + c * 16 + (u_hi + 2) * 4;
      if (vj_hi) {
        size_t i0 = base + jhi * 256 + v_hi;
        s += bf2f(A0[i0]) + bf2f(A1[i0]);
      }
      if (vj_lo) {
        size_t i0 = base + (jhi - 1) * 256 + v_hi + 2;
        s += bf2f(A0[i0]) + bf2f(A1[i0]);
      }
    }
    size_t xi = (((size_t)b * 16 + c) * 128 + h) * 128 + w;
    out[xi] = x[xi] + al * s;
  }
}

extern "C" void kernel_launch(void* const* d_in, const int* in_sizes, int n_in,
                              void* d_out, int out_size, void* d_ws, size_t ws_size,
                              hipStream_t stream) {
  const float* x      = (const float*)d_in[0];
  const float* scores = (const float*)d_in[1];
  const float* alpha  = (const float*)d_in[2];
  float* out = (float*)d_out;

  // ws: VmatT bf16 16 MB | AmatP bf16 2 x 16 MB
  unsigned short* vmatT = (unsigned short*)d_ws;
  unsigned short* AmatP = (unsigned short*)((char*)d_ws + (size_t)16 * 1024 * 1024);

  prep_vmat<<<4096, 256, 0, stream>>>(x, vmatT);
  gemm_scores_vmat<<<256, 512, 0, stream>>>(scores, vmatT, AmatP);
  epilogue_kernel<<<1024, 256, 0, stream>>>(x, AmatP, alpha, out);
}

// Round 16
// 162.325 us; speedup vs baseline: 2.1201x; 2.1201x over previous
//
#include <hip/hip_runtime.h>
#include <hip/hip_bf16.h>

typedef float f32x4 __attribute__((ext_vector_type(4)));
typedef short bf16x8 __attribute__((ext_vector_type(8)));
typedef unsigned short us8 __attribute__((ext_vector_type(8)));
typedef unsigned short us4 __attribute__((ext_vector_type(4)));

__device__ __forceinline__ unsigned short f2bf(float f) {
  union { float f; unsigned u; } v; v.f = f;
  return (unsigned short)((v.u + 0x8000u) >> 16);   // round-half-up bf16
}
__device__ __forceinline__ float bf2f(unsigned short u) {
  union { unsigned u; float f; } v; v.u = ((unsigned)u) << 16;
  return v.f;
}

// ---------------------------------------------------------------------------
// Kernel 1: VmatT[b][n][p] (bf16), n = c*16+u*4+v (256), p = pi*64+pj (4096)
// ---------------------------------------------------------------------------
__global__ __launch_bounds__(256) void prep_vmat(const float* __restrict__ x,
                                                 unsigned short* __restrict__ vmatT) {
  int t = blockIdx.x * 256 + threadIdx.x;
  int pc = t & 511;
  int n  = (t >> 9) & 255;
  int b  = t >> 17;
  int c = n >> 4, u = (n >> 2) & 3, v = n & 3;
  int pi = pc >> 3;
  int pj0 = (pc & 7) << 3;
  int row = 2 * pi + u - 1;
  row = row < 0 ? 0 : (row > 127 ? 127 : row);
  const float* xr = x + ((size_t)(b * 16 + c) * 128 + row) * 128;
  us8 o;
#pragma unroll
  for (int e = 0; e < 8; ++e) {
    int col = 2 * (pj0 + e) + v - 1;
    col = col < 0 ? 0 : (col > 127 ? 127 : col);
    o[e] = f2bf(xr[col]);
  }
  *reinterpret_cast<us8*>(vmatT + (size_t)t * 8) = o;
}

// ---------------------------------------------------------------------------
// Kernel 2: EXACT R13 GEMM (measured 172.9 us total). Deep-FIFO: BQ=128
// (512 thr, 8 waves M-split), BK=64, 64 K-tiles, B ring-4 (128 KB LDS),
// A reg-staged 4 ahead, B staged 2 ahead, vmcnt(12) leaves 96 KB/CU in
// flight across every barrier. R14 proved deeper FIFO is null; R15's
// fatter tiles spilled. Do not touch.
// ---------------------------------------------------------------------------
__global__ __launch_bounds__(512, 2) void gemm_scores_vmat(
    const float* __restrict__ scores,
    const unsigned short* __restrict__ vmatT,
    unsigned short* __restrict__ Amat) {
  __shared__ unsigned short ldsB[4][16384];   // 4 x (256 rows x 64 bf16)

  int bid = blockIdx.x;                        // 256 blocks = 1/CU
  int batch = bid & 7;                         // = XCD id
  int qb = (bid >> 3) << 7;                    // 32 q-blocks of 128
  const int phase = ((bid >> 3) * 2) & 63;

  const int t = threadIdx.x;
  const int lane = t & 63;
  const int wq = t >> 6;                       // wave id 0..7 = M slice
  const int l15 = lane & 15, l16 = lane >> 4;

  const float* aLane =
      scores + ((size_t)(batch * 4096 + qb + wq * 16 + l15)) * 4096 + l16 * 8;
  const unsigned short* Vb = vmatT + (size_t)batch * 256 * 4096;

  const unsigned short* bSrc[4];
#pragma unroll
  for (int i = 0; i < 4; ++i) {
    int c = t + i * 512;
    int gs = (c & 7) ^ ((c >> 3) & 7);
    bSrc[i] = Vb + (size_t)(c >> 3) * 4096 + gs * 8;
  }
  const int pos0 = (l16 ^ (l15 & 7)) << 3;

  f32x4 acc[16];
#pragma unroll
  for (int ni = 0; ni < 16; ++ni) acc[ni] = (f32x4){0.f, 0.f, 0.f, 0.f};

  f32x4 r0[4], r1[4], r2[4], r3[4];
  bf16x8 fa0, fa1;

#define SB __builtin_amdgcn_sched_barrier(0)
#define STAGE_B(kt, bufi)                                                     \
  {                                                                           \
    int kp_ = ((kt) + phase) & 63;                                            \
    _Pragma("unroll") for (int i = 0; i < 4; ++i)                             \
        __builtin_amdgcn_global_load_lds(                                     \
            (const __attribute__((address_space(1))) void*)(bSrc[i] + (size_t)kp_ * 64), \
            (__attribute__((address_space(3))) void*)&ldsB[bufi][(t + i * 512) * 8], \
            16, 0, 0);                                                        \
  }
#define LOAD_A(kt, rr)                                                        \
  {                                                                           \
    int kp_ = ((kt) + phase) & 63;                                            \
    const float* ap_ = aLane + (size_t)kp_ * 64;                              \
    rr[0] = *(const f32x4*)(ap_);                                             \
    rr[1] = *(const f32x4*)(ap_ + 4);                                         \
    rr[2] = *(const f32x4*)(ap_ + 32);                                        \
    rr[3] = *(const f32x4*)(ap_ + 36);                                        \
  }
#define CONV(rr)                                                              \
  {                                                                           \
    _Pragma("unroll") for (int e = 0; e < 4; ++e) {                           \
      fa0[e] = (short)f2bf(rr[0][e]); fa0[e + 4] = (short)f2bf(rr[1][e]);     \
      fa1[e] = (short)f2bf(rr[2][e]); fa1[e + 4] = (short)f2bf(rr[3][e]);     \
    }                                                                         \
  }
#define MFMAS(bufi)                                                           \
  {                                                                           \
    _Pragma("unroll") for (int ni = 0; ni < 16; ++ni) {                       \
      bf16x8 bv = *(const bf16x8*)(&ldsB[bufi][0] +                           \
                                   (ni * 16 + l15) * 64 + pos0);              \
      acc[ni] = __builtin_amdgcn_mfma_f32_16x16x32_bf16(fa0, bv, acc[ni],     \
                                                        0, 0, 0);             \
    }                                                                         \
    _Pragma("unroll") for (int ni = 0; ni < 16; ++ni) {                       \
      bf16x8 bv = *(const bf16x8*)(&ldsB[bufi][0] +                           \
                                   (ni * 16 + l15) * 64 + (pos0 ^ 32));      \
      acc[ni] = __builtin_amdgcn_mfma_f32_16x16x32_bf16(fa1, bv, acc[ni],     \
                                                        0, 0, 0);             \
    }                                                                         \
  }
#define BODY(m, kt, rr)                                                       \
  {                                                                           \
    CONV(rr);                                                                 \
    SB;                                                                       \
    STAGE_B((kt) + 2, ((m) + 2) & 3);                                         \
    SB;                                                                       \
    LOAD_A((kt) + 4, rr);                                                     \
    SB;                                                                       \
    MFMAS(m);                                                                 \
    SB;                                                                       \
    asm volatile("s_waitcnt vmcnt(12)" ::: "memory");                         \
    SB;                                                                       \
    __builtin_amdgcn_s_barrier();                                             \
    SB;                                                                       \
  }

  STAGE_B(0, 0);
  SB;
  LOAD_A(0, r0);
  SB;
  LOAD_A(1, r1);
  SB;
  LOAD_A(2, r2);
  SB;
  STAGE_B(1, 1);
  SB;
  LOAD_A(3, r3);
  SB;
  asm volatile("s_waitcnt vmcnt(12)" ::: "memory");
  SB;
  __builtin_amdgcn_s_barrier();
  SB;

  for (int kt = 0; kt < 64; kt += 4) {
    BODY(0, kt, r0);
    BODY(1, kt + 1, r1);
    BODY(2, kt + 2, r2);
    BODY(3, kt + 3, r3);
  }

  asm volatile("" ::"v"(r0[0][0]), "v"(r1[0][0]), "v"(r2[0][0]), "v"(r3[0][0]),
               "v"(r0[3][0]), "v"(r1[3][0]), "v"(r2[3][0]), "v"(r3[3][0]));

#undef SB
#undef STAGE_B
#undef LOAD_A
#undef CONV
#undef MFMAS
#undef BODY

  unsigned short* Ao = Amat + ((size_t)(batch * 4096 + qb + wq * 16)) * 256;
#pragma unroll
  for (int ni = 0; ni < 16; ++ni)
#pragma unroll
    for (int j = 0; j < 4; ++j)
      Ao[(size_t)(l16 * 4 + j) * 256 + ni * 16 + l15] = f2bf(acc[ni][j]);
}

// ---------------------------------------------------------------------------
// Kernel 3 (REWRITTEN): coalesced LDS-staged epilogue.
// Per (b,h) block the 4 conv_transpose contributions come from exactly two
// 8-KB u-planes of Amat: P0 = row-block ihi (u=u_hi), P1 = row-block ihi-1
// (u=u_hi+2); invalid planes (edge h) are zero-filled. Old version read A
// with 512-B lane stride (2-B loads -> ~64 L1 txns per wave-instr, ~20 us
// of scatter). New: stage planes with sequential 8-B chunks, gather from
// LDS [2][64][66] (132-B rows -> bank advance 33 == 1 mod 32, conflict-free).
// ---------------------------------------------------------------------------
__global__ __launch_bounds__(256) void epilogue_kernel(
    const float* __restrict__ x, const unsigned short* __restrict__ Amat,
    const float* __restrict__ alpha, float* __restrict__ out) {
  __shared__ unsigned short L[2 * 64 * 66];   // plane p, row j, col cv (c*4+v)

  int b = blockIdx.x >> 7;
  int h = blockIdx.x & 127;
  int t = threadIdx.x;

  int ihi = (h + 1) >> 1, u_hi = (h + 1) & 1;
  bool p0ok = (ihi <= 63), p1ok = (ihi >= 1);
  const unsigned short* Ab = Amat + (size_t)b * 4096 * 256;

  // stage: plane p, chunk q = t + 256*i -> j = q>>4, c = q&15 (8 B = 4 v)
  unsigned int* Lw = reinterpret_cast<unsigned int*>(L);
#pragma unroll
  for (int p = 0; p < 2; ++p) {
    bool ok = p ? p1ok : p0ok;
    int rbase = (p ? (ihi - 1) : ihi) * 64;
    int u = u_hi + 2 * p;
#pragma unroll
    for (int i = 0; i < 4; ++i) {
      int q = t + 256 * i;
      int j = q >> 4, c = q & 15;
      us4 ch = (us4){0, 0, 0, 0};
      if (ok)
        ch = *reinterpret_cast<const us4*>(Ab + (size_t)(rbase + j) * 256 +
                                           c * 16 + u * 4);
      int widx = (p * 4224 + j * 66 + c * 4) >> 1;   // elem idx / 2 (even)
      Lw[widx]     = (unsigned int)(unsigned short)ch[0] |
                     ((unsigned int)(unsigned short)ch[1] << 16);
      Lw[widx + 1] = (unsigned int)(unsigned short)ch[2] |
                     ((unsigned int)(unsigned short)ch[3] << 16);
    }
  }
  __syncthreads();

  int w = t & 127;
  int cg = t >> 7;
  int jhi = (w + 1) >> 1, v_hi = (w + 1) & 1;
  bool vj_hi = (jhi <= 63), vj_lo = (jhi >= 1);
  float al = alpha[0] * 0.25f;

#pragma unroll
  for (int cc = 0; cc < 8; ++cc) {
    int c = cg * 8 + cc;
    float s = 0.f;
    if (vj_hi) {
      int o = jhi * 66 + c * 4 + v_hi;
      s += bf2f(L[o]) + bf2f(L[4224 + o]);
    }
    if (vj_lo) {
      int o = (jhi - 1) * 66 + c * 4 + v_hi + 2;
      s += bf2f(L[o]) + bf2f(L[4224 + o]);
    }
    size_t xi = (((size_t)b * 16 + c) * 128 + h) * 128 + w;
    out[xi] = x[xi] + al * s;
  }
}

extern "C" void kernel_launch(void* const* d_in, const int* in_sizes, int n_in,
                              void* d_out, int out_size, void* d_ws, size_t ws_size,
                              hipStream_t stream) {
  const float* x      = (const float*)d_in[0];
  const float* scores = (const float*)d_in[1];
  const float* alpha  = (const float*)d_in[2];
  float* out = (float*)d_out;

  unsigned short* vmatT = (unsigned short*)d_ws;
  unsigned short* Amat  = (unsigned short*)((char*)d_ws + (size_t)16 * 1024 * 1024);

  prep_vmat<<<4096, 256, 0, stream>>>(x, vmatT);
  gemm_scores_vmat<<<256, 512, 0, stream>>>(scores, vmatT, Amat);
  epilogue_kernel<<<1024, 256, 0, stream>>>(x, Amat, alpha, out);
}